// Round 3
// baseline (352.432 us; speedup 1.0000x reference)
//
#include <hip/hip_runtime.h>

#define N_SAMP 8192
#define D_DIM 6144
#define K_CLS 10
#define CHUNK 32
#define NCHUNKS (N_SAMP / CHUNK)          // 256
#define COLS_PER_BLOCK 1024               // 256 threads * 4 floats
#define NGROUPS (D_DIM / COLS_PER_BLOCK)  // 6
#define PIPE 8                            // outstanding loads per thread

// Kernel A: atomic-free counting sort of sample indices by class.
// 256 threads; thread t owns labels [t*32, t*32+32). Also zeroes S1/s2sum/out
// (replaces two hipMemsetAsync dispatches). sorted[] packs (class<<16 | idx).
__global__ __launch_bounds__(256) void build_sort(const int* __restrict__ y,
                                                  int* __restrict__ counts,
                                                  int* __restrict__ sorted,
                                                  float* __restrict__ S1,
                                                  float* __restrict__ s2sum,
                                                  float* __restrict__ out) {
    __shared__ int M[K_CLS * 256];   // per-(class,thread) hist -> scan offsets
    __shared__ int wsum[4];
    const int tid = threadIdx.x;
    const int lane = tid & 63;
    const int wid = tid >> 6;

    // zero workspace accumulators (stream order guarantees visibility to accum)
    for (int j = tid; j < K_CLS * D_DIM; j += 256) S1[j] = 0.0f;
    if (tid < K_CLS) s2sum[tid] = 0.0f;
    if (tid == 0) out[0] = 0.0f;

    // phase 1: per-thread histogram over 32 contiguous labels
    int h[K_CLS];
#pragma unroll
    for (int k = 0; k < K_CLS; ++k) h[k] = 0;
    const int base = tid * 32;
#pragma unroll 1
    for (int i = 0; i < 32; ++i) {
        const int yy = y[base + i];
#pragma unroll
        for (int k = 0; k < K_CLS; ++k) h[k] += (yy == k) ? 1 : 0;
    }
#pragma unroll
    for (int k = 0; k < K_CLS; ++k) M[k * 256 + tid] = h[k];
    __syncthreads();

    // phase 2: block-wide exclusive scan over M viewed flat [2560] class-major.
    // thread scans its 10 consecutive flat elems, then shuffle-scan of sums.
    int loc[10];
    int run = 0;
#pragma unroll
    for (int j = 0; j < 10; ++j) { loc[j] = run; run += M[tid * 10 + j]; }
    int v = run;
#pragma unroll
    for (int d = 1; d < 64; d <<= 1) {
        int n = __shfl_up(v, d, 64);
        if (lane >= d) v += n;
    }
    if (lane == 63) wsum[wid] = v;
    __syncthreads();
    int wbase = 0;
#pragma unroll
    for (int w = 0; w < 4; ++w) wbase += (w < wid) ? wsum[w] : 0;
    const int tbase = wbase + (v - run);   // exclusive scan of per-thread sums
    __syncthreads();
#pragma unroll
    for (int j = 0; j < 10; ++j) M[tid * 10 + j] = tbase + loc[j];
    __syncthreads();

    // per-class counts from scan values at class boundaries
    if (tid < K_CLS) {
        const int s = M[tid * 256];
        const int e = (tid == K_CLS - 1) ? N_SAMP : M[(tid + 1) * 256];
        counts[tid] = e - s;
    }

    // phase 3: stable scatter, packing class into high bits
    int off[K_CLS];
#pragma unroll
    for (int k = 0; k < K_CLS; ++k) off[k] = M[k * 256 + tid];
#pragma unroll 1
    for (int i = 0; i < 32; ++i) {
        const int yy = y[base + i];
#pragma unroll
        for (int k = 0; k < K_CLS; ++k)
            if (yy == k) sorted[off[k]++] = (k << 16) | (base + i);
    }
}

// Kernel B: class-sorted accumulation. Depth-8 rotating register pipeline
// keeps 8 float4 loads in flight per thread. Per-thread state: S1 float4 for
// its 4 columns + column-reduced S2 scalar, flushed on (wave-uniform, rare)
// class boundary.
__global__ __launch_bounds__(256) void wcss_accum(const float* __restrict__ X,
                                                  const int* __restrict__ sorted,
                                                  float* __restrict__ S1,
                                                  float* __restrict__ s2sum) {
    __shared__ int idx_lds[CHUNK];
    __shared__ int cls_lds[CHUNK];
    const int tid = threadIdx.x;
    const int col0 = blockIdx.x * COLS_PER_BLOCK + tid * 4;
    const int s0g = blockIdx.y * CHUNK;

    if (tid < CHUNK) {
        const int p = sorted[s0g + tid];
        idx_lds[tid] = p & 0xffff;
        cls_lds[tid] = p >> 16;
    }
    __syncthreads();

    const float* base = X + col0;
    float4 a1 = make_float4(0.f, 0.f, 0.f, 0.f);
    float s2c = 0.f;
    int kcur = __builtin_amdgcn_readfirstlane(cls_lds[0]);

    float4 buf[PIPE];
#pragma unroll
    for (int j = 0; j < PIPE; ++j)
        buf[j] = *(const float4*)(base + (size_t)idx_lds[j] * D_DIM);

#pragma unroll
    for (int s = 0; s < CHUNK; ++s) {
        const float4 v = buf[s & (PIPE - 1)];
        if (s + PIPE < CHUNK)   // compile-time after unroll
            buf[s & (PIPE - 1)] =
                *(const float4*)(base + (size_t)idx_lds[s + PIPE] * D_DIM);

        const int yk = __builtin_amdgcn_readfirstlane(cls_lds[s]);
        if (yk != kcur) {   // uniform branch, ~1 per block
            float* b1 = S1 + kcur * D_DIM + col0;
            atomicAdd(b1 + 0, a1.x); atomicAdd(b1 + 1, a1.y);
            atomicAdd(b1 + 2, a1.z); atomicAdd(b1 + 3, a1.w);
            atomicAdd(&s2sum[kcur], s2c);
            a1 = make_float4(0.f, 0.f, 0.f, 0.f);
            s2c = 0.f;
            kcur = yk;
        }
        a1.x += v.x; a1.y += v.y; a1.z += v.z; a1.w += v.w;
        s2c += v.x * v.x + v.y * v.y + v.z * v.z + v.w * v.w;
    }

    float* b1 = S1 + kcur * D_DIM + col0;
    atomicAdd(b1 + 0, a1.x); atomicAdd(b1 + 1, a1.y);
    atomicAdd(b1 + 2, a1.z); atomicAdd(b1 + 3, a1.w);
    atomicAdd(&s2sum[kcur], s2c);
}

// Kernel C: 60 blocks (class k x column-slice g). Per cell add
// -S1^2/(cnt^2*D*K); one thread also adds S2sum_k/(cnt*D*K).
__global__ __launch_bounds__(256) void wcss_finish(const float* __restrict__ S1,
                                                   const float* __restrict__ s2sum,
                                                   const int* __restrict__ counts,
                                                   float* __restrict__ out) {
    __shared__ float sbuf[256];
    const int tid = threadIdx.x;
    const int k = blockIdx.x / NGROUPS;
    const int g = blockIdx.x % NGROUPS;
    const float cnt = (float)counts[k];
    const float inv = 1.0f / (cnt * cnt * (float)D_DIM * (float)K_CLS);

    const float4 v = *(const float4*)(S1 + k * D_DIM + g * COLS_PER_BLOCK + tid * 4);
    float t = -(v.x * v.x + v.y * v.y + v.z * v.z + v.w * v.w) * inv;
    if (g == 0 && tid == 0)
        t += s2sum[k] / (cnt * (float)D_DIM * (float)K_CLS);

    sbuf[tid] = t;
    __syncthreads();
    for (int off = 128; off > 0; off >>= 1) {
        if (tid < off) sbuf[tid] += sbuf[tid + off];
        __syncthreads();
    }
    if (tid == 0) atomicAdd(out, sbuf[0]);
}

extern "C" void kernel_launch(void* const* d_in, const int* in_sizes, int n_in,
                              void* d_out, int out_size, void* d_ws, size_t ws_size,
                              hipStream_t stream) {
    const float* X = (const float*)d_in[0];
    const int* y = (const int*)d_in[1];

    float* S1 = (float*)d_ws;                       // K*D floats
    float* s2sum = S1 + K_CLS * D_DIM;              // K floats
    int* counts = (int*)(s2sum + K_CLS);            // K ints
    int* sorted = counts + K_CLS;                   // N ints
    float* out = (float*)d_out;

    build_sort<<<dim3(1), dim3(256), 0, stream>>>(y, counts, sorted, S1, s2sum, out);
    wcss_accum<<<dim3(NGROUPS, NCHUNKS), dim3(256), 0, stream>>>(X, sorted, S1, s2sum);
    wcss_finish<<<dim3(K_CLS * NGROUPS), dim3(256), 0, stream>>>(S1, s2sum, counts, out);
}

// Round 4
// 299.930 us; speedup vs baseline: 1.1750x; 1.1750x over previous
//
#include <hip/hip_runtime.h>

#define N_SAMP 8192
#define D_DIM 6144
#define K_CLS 10
#define CHUNK 64
#define COLS_PER_BLOCK 1024               // 256 threads * 4 floats
#define NGROUPS (D_DIM / COLS_PER_BLOCK)  // 6
#define MAXRUNS 144                       // ceil(8192/64)=128 runs + <=10 split + pad
#define PIPE 8                            // outstanding float4 loads per thread

// Kernel A: 1024-thread atomic-free counting sort by class. Emits:
//   sorted[]  (class<<16 | sample idx), class-contiguous
//   counts[k], runs[] = (start, len<=64) class-uniform segments (len=0 pad)
// Also zeroes S1 / s2sum / out (no memset dispatches needed).
__global__ __launch_bounds__(1024) void build_sort(const int* __restrict__ y,
                                                   int* __restrict__ counts,
                                                   int* __restrict__ sorted,
                                                   int2* __restrict__ runs,
                                                   float* __restrict__ S1,
                                                   float* __restrict__ s2sum,
                                                   float* __restrict__ out) {
    __shared__ int M[K_CLS * 1024];
    __shared__ int wsum[16];
    __shared__ int Bnd[K_CLS + 1];
    const int tid = threadIdx.x;
    const int lane = tid & 63;
    const int wid = tid >> 6;

    // zero accumulators (stream order makes this visible to wcss_accum)
    const float4 z4 = make_float4(0.f, 0.f, 0.f, 0.f);
    for (int j = tid; j < K_CLS * D_DIM / 4; j += 1024) ((float4*)S1)[j] = z4;
    if (tid < K_CLS) s2sum[tid] = 0.f;
    if (tid == 0) out[0] = 0.f;

    // phase 1: per-thread histogram over 8 contiguous labels (int4 loads)
    const int base = tid * 8;
    const int4 ya = ((const int4*)y)[tid * 2];
    const int4 yb = ((const int4*)y)[tid * 2 + 1];
    int yy[8] = {ya.x, ya.y, ya.z, ya.w, yb.x, yb.y, yb.z, yb.w};
    int h[K_CLS];
#pragma unroll
    for (int k = 0; k < K_CLS; ++k) h[k] = 0;
#pragma unroll
    for (int i = 0; i < 8; ++i)
#pragma unroll
        for (int k = 0; k < K_CLS; ++k) h[k] += (yy[i] == k) ? 1 : 0;
#pragma unroll
    for (int k = 0; k < K_CLS; ++k) M[k * 1024 + tid] = h[k];
    __syncthreads();

    // phase 2: block exclusive scan over M flat [10240], class-major
    int loc[K_CLS];
    int run = 0;
#pragma unroll
    for (int j = 0; j < K_CLS; ++j) { loc[j] = run; run += M[tid * K_CLS + j]; }
    int v = run;
#pragma unroll
    for (int d = 1; d < 64; d <<= 1) {
        int n = __shfl_up(v, d, 64);
        if (lane >= d) v += n;
    }
    if (lane == 63) wsum[wid] = v;
    __syncthreads();
    int wbase = 0;
#pragma unroll
    for (int w = 0; w < 16; ++w) wbase += (w < wid) ? wsum[w] : 0;
    const int tbase = wbase + (v - run);
    __syncthreads();
#pragma unroll
    for (int j = 0; j < K_CLS; ++j) M[tid * K_CLS + j] = tbase + loc[j];
    __syncthreads();

    if (tid < K_CLS) Bnd[tid] = M[tid * 1024];
    if (tid == 0) Bnd[K_CLS] = N_SAMP;
    __syncthreads();
    if (tid < K_CLS) counts[tid] = Bnd[tid + 1] - Bnd[tid];

    // run table: split each class segment into <=64-sample runs
    if (tid == 0) {
        int r = 0;
        for (int k = 0; k < K_CLS; ++k)
            for (int p = Bnd[k]; p < Bnd[k + 1]; p += CHUNK) {
                int l = Bnd[k + 1] - p;
                if (l > CHUNK) l = CHUNK;
                runs[r++] = make_int2(p, l);
            }
        for (; r < MAXRUNS; ++r) runs[r] = make_int2(0, 0);
    }

    // phase 3: stable scatter with class packed into high bits
    int off[K_CLS];
#pragma unroll
    for (int k = 0; k < K_CLS; ++k) off[k] = M[k * 1024 + tid];
#pragma unroll
    for (int i = 0; i < 8; ++i)
#pragma unroll
        for (int k = 0; k < K_CLS; ++k)
            if (yy[i] == k) sorted[off[k]++] = (k << 16) | (base + i);
}

// Kernel B: one block = one class-uniform run x one 1024-column slice.
// Branch-free inner loop, 8-deep rotating load pipeline (const indices via
// full unroll). Flush once: 4 spread S1 atomics/thread + ONE s2 atomic/block.
__global__ __launch_bounds__(256) void wcss_accum(const float* __restrict__ X,
                                                  const int* __restrict__ sorted,
                                                  const int2* __restrict__ runs,
                                                  float* __restrict__ S1,
                                                  float* __restrict__ s2sum) {
    __shared__ int off_lds[CHUNK];   // precomputed row byte-offsets
    __shared__ int cls0;
    __shared__ float wred[4];
    const int tid = threadIdx.x;
    const int lane = tid & 63;
    const int wid = tid >> 6;

    const int2 rn = runs[blockIdx.y];
    const int len = rn.y;
    if (len == 0) return;

    if (tid < CHUNK && tid < len) {
        const int p = sorted[rn.x + tid];
        off_lds[tid] = (p & 0xffff) * (D_DIM * (int)sizeof(float));
        if (tid == 0) cls0 = p >> 16;
    }
    __syncthreads();
    const int kcls = __builtin_amdgcn_readfirstlane(cls0);
    const char* basep = (const char*)(X + blockIdx.x * COLS_PER_BLOCK + tid * 4);

    float4 a1 = make_float4(0.f, 0.f, 0.f, 0.f);
    float s2c = 0.f;

    float4 buf[PIPE];
#pragma unroll
    for (int j = 0; j < PIPE; ++j) {
        const int ix = (j < len) ? j : len - 1;
        buf[j] = *(const float4*)(basep + (size_t)off_lds[ix]);
    }

    int s8 = 0;
#pragma unroll 1
    for (; s8 + PIPE <= len; s8 += PIPE) {
#pragma unroll
        for (int j = 0; j < PIPE; ++j) {
            const float4 v = buf[j];
            int nx = s8 + PIPE + j;
            nx = (nx < len) ? nx : len - 1;
            buf[j] = *(const float4*)(basep + (size_t)off_lds[nx]);
            a1.x += v.x; a1.y += v.y; a1.z += v.z; a1.w += v.w;
            s2c += v.x * v.x + v.y * v.y + v.z * v.z + v.w * v.w;
        }
    }
#pragma unroll
    for (int j = 0; j < PIPE; ++j)
        if (s8 + j < len) {
            const float4 v = buf[j];
            a1.x += v.x; a1.y += v.y; a1.z += v.z; a1.w += v.w;
            s2c += v.x * v.x + v.y * v.y + v.z * v.z + v.w * v.w;
        }

    // flush S1 (spread addresses)
    float* b1 = S1 + kcls * D_DIM + blockIdx.x * COLS_PER_BLOCK + tid * 4;
    atomicAdd(b1 + 0, a1.x); atomicAdd(b1 + 1, a1.y);
    atomicAdd(b1 + 2, a1.z); atomicAdd(b1 + 3, a1.w);

    // s2: block reduce -> single atomic per block
#pragma unroll
    for (int o = 32; o > 0; o >>= 1) s2c += __shfl_down(s2c, o, 64);
    if (lane == 0) wred[wid] = s2c;
    __syncthreads();
    if (tid == 0) atomicAdd(&s2sum[kcls], wred[0] + wred[1] + wred[2] + wred[3]);
}

// Kernel C: 60 blocks (class k x column-slice g). Per cell add
// -S1^2/(cnt^2*D*K); one thread also adds S2sum_k/(cnt*D*K).
__global__ __launch_bounds__(256) void wcss_finish(const float* __restrict__ S1,
                                                   const float* __restrict__ s2sum,
                                                   const int* __restrict__ counts,
                                                   float* __restrict__ out) {
    __shared__ float sbuf[256];
    const int tid = threadIdx.x;
    const int k = blockIdx.x / NGROUPS;
    const int g = blockIdx.x % NGROUPS;
    const float cnt = (float)counts[k];
    const float inv = 1.0f / (cnt * cnt * (float)D_DIM * (float)K_CLS);

    const float4 v = *(const float4*)(S1 + k * D_DIM + g * COLS_PER_BLOCK + tid * 4);
    float t = -(v.x * v.x + v.y * v.y + v.z * v.z + v.w * v.w) * inv;
    if (g == 0 && tid == 0)
        t += s2sum[k] / (cnt * (float)D_DIM * (float)K_CLS);

    sbuf[tid] = t;
    __syncthreads();
    for (int off = 128; off > 0; off >>= 1) {
        if (tid < off) sbuf[tid] += sbuf[tid + off];
        __syncthreads();
    }
    if (tid == 0) atomicAdd(out, sbuf[0]);
}

extern "C" void kernel_launch(void* const* d_in, const int* in_sizes, int n_in,
                              void* d_out, int out_size, void* d_ws, size_t ws_size,
                              hipStream_t stream) {
    const float* X = (const float*)d_in[0];
    const int* y = (const int*)d_in[1];

    float* S1 = (float*)d_ws;                       // K*D floats
    float* s2sum = S1 + K_CLS * D_DIM;              // K floats
    int* counts = (int*)(s2sum + K_CLS);            // K ints
    int* sorted = counts + K_CLS;                   // N ints
    int2* runs = (int2*)(sorted + N_SAMP);          // MAXRUNS int2
    float* out = (float*)d_out;

    build_sort<<<dim3(1), dim3(1024), 0, stream>>>(y, counts, sorted, runs,
                                                   S1, s2sum, out);
    wcss_accum<<<dim3(NGROUPS, MAXRUNS), dim3(256), 0, stream>>>(X, sorted, runs,
                                                                 S1, s2sum);
    wcss_finish<<<dim3(K_CLS * NGROUPS), dim3(256), 0, stream>>>(S1, s2sum,
                                                                 counts, out);
}

// Round 5
// 297.287 us; speedup vs baseline: 1.1855x; 1.0089x over previous
//
#include <hip/hip_runtime.h>

#define N_SAMP 8192
#define D_DIM 6144
#define K_CLS 10
#define CHUNK 32
#define NWIN (N_SAMP / CHUNK)             // 256 windows, always full
#define COLS_PER_BLOCK 1024               // 256 threads * 4 floats
#define NGROUPS (D_DIM / COLS_PER_BLOCK)  // 6  -> grid 1536 = 6 blocks/CU even
#define PIPE 8                            // outstanding float4 loads per thread

// Kernel A: 1024-thread atomic-free counting sort by class.
// sorted[] packs (class<<16 | sample idx), class-contiguous. counts[k] out.
__global__ __launch_bounds__(1024) void build_sort(const int* __restrict__ y,
                                                   int* __restrict__ counts,
                                                   int* __restrict__ sorted) {
    __shared__ int M[K_CLS * 1024];
    __shared__ int wsum[16];
    const int tid = threadIdx.x;
    const int lane = tid & 63;
    const int wid = tid >> 6;

    // per-thread histogram over 8 contiguous labels (int4 loads)
    const int base = tid * 8;
    const int4 ya = ((const int4*)y)[tid * 2];
    const int4 yb = ((const int4*)y)[tid * 2 + 1];
    int yy[8] = {ya.x, ya.y, ya.z, ya.w, yb.x, yb.y, yb.z, yb.w};
    int h[K_CLS];
#pragma unroll
    for (int k = 0; k < K_CLS; ++k) h[k] = 0;
#pragma unroll
    for (int i = 0; i < 8; ++i)
#pragma unroll
        for (int k = 0; k < K_CLS; ++k) h[k] += (yy[i] == k) ? 1 : 0;
#pragma unroll
    for (int k = 0; k < K_CLS; ++k) M[k * 1024 + tid] = h[k];
    __syncthreads();

    // block exclusive scan over M flat [10240], class-major
    int loc[K_CLS];
    int run = 0;
#pragma unroll
    for (int j = 0; j < K_CLS; ++j) { loc[j] = run; run += M[tid * K_CLS + j]; }
    int v = run;
#pragma unroll
    for (int d = 1; d < 64; d <<= 1) {
        int n = __shfl_up(v, d, 64);
        if (lane >= d) v += n;
    }
    if (lane == 63) wsum[wid] = v;
    __syncthreads();
    int wbase = 0;
#pragma unroll
    for (int w = 0; w < 16; ++w) wbase += (w < wid) ? wsum[w] : 0;
    const int tbase = wbase + (v - run);
    __syncthreads();
#pragma unroll
    for (int j = 0; j < K_CLS; ++j) M[tid * K_CLS + j] = tbase + loc[j];
    __syncthreads();

    if (tid < K_CLS) {
        const int s = M[tid * 1024];
        const int e = (tid == K_CLS - 1) ? N_SAMP : M[(tid + 1) * 1024];
        counts[tid] = e - s;
    }

    // stable scatter, class packed in high bits
    int off[K_CLS];
#pragma unroll
    for (int k = 0; k < K_CLS; ++k) off[k] = M[k * 1024 + tid];
#pragma unroll
    for (int i = 0; i < 8; ++i)
#pragma unroll
        for (int k = 0; k < K_CLS; ++k)
            if (yy[i] == k) sorted[off[k]++] = (k << 16) | (base + i);
}

// Kernel B: one block = one full 32-sample sorted window x one 1024-col slice.
// 1536 blocks = exactly 6/CU. 8-deep rotating register load pipeline. Class
// boundary inside a window is rare (<=9 across all 256 windows) and
// block-uniform -> scalar branch with block-reduced s2 flush.
__global__ __launch_bounds__(256) void wcss_accum(const float* __restrict__ X,
                                                  const int* __restrict__ sorted,
                                                  float* __restrict__ S1,
                                                  float* __restrict__ s2sum) {
    __shared__ int off_lds[CHUNK];   // row byte-offsets
    __shared__ int cls_lds[CHUNK];
    __shared__ float wred[4];
    const int tid = threadIdx.x;
    const int lane = tid & 63;
    const int wid = tid >> 6;
    const int col0 = blockIdx.x * COLS_PER_BLOCK + tid * 4;

    if (tid < CHUNK) {
        const int p = sorted[blockIdx.y * CHUNK + tid];
        off_lds[tid] = (p & 0xffff) * (D_DIM * (int)sizeof(float));
        cls_lds[tid] = p >> 16;
    }
    __syncthreads();

    const char* basep = (const char*)(X + col0);
    float4 a1 = make_float4(0.f, 0.f, 0.f, 0.f);
    float s2c = 0.f;
    int kcur = __builtin_amdgcn_readfirstlane(cls_lds[0]);

    float4 buf[PIPE];
#pragma unroll
    for (int j = 0; j < PIPE; ++j)
        buf[j] = *(const float4*)(basep + (size_t)off_lds[j]);

#pragma unroll
    for (int s = 0; s < CHUNK; ++s) {
        const float4 v = buf[s & (PIPE - 1)];
        if (s + PIPE < CHUNK)   // compile-time after full unroll
            buf[s & (PIPE - 1)] =
                *(const float4*)(basep + (size_t)off_lds[s + PIPE]);

        const int yk = __builtin_amdgcn_readfirstlane(cls_lds[s]);
        if (yk != kcur) {   // block-uniform scalar branch, rare
            float* b1 = S1 + kcur * D_DIM + col0;
            atomicAdd(b1 + 0, a1.x); atomicAdd(b1 + 1, a1.y);
            atomicAdd(b1 + 2, a1.z); atomicAdd(b1 + 3, a1.w);
            float r = s2c;
#pragma unroll
            for (int o = 32; o > 0; o >>= 1) r += __shfl_down(r, o, 64);
            if (lane == 0) wred[wid] = r;
            __syncthreads();   // legal: branch is block-uniform
            if (tid == 0)
                atomicAdd(&s2sum[kcur], wred[0] + wred[1] + wred[2] + wred[3]);
            __syncthreads();
            a1 = make_float4(0.f, 0.f, 0.f, 0.f);
            s2c = 0.f;
            kcur = yk;
        }
        a1.x += v.x; a1.y += v.y; a1.z += v.z; a1.w += v.w;
        s2c += v.x * v.x + v.y * v.y + v.z * v.z + v.w * v.w;
    }

    // final flush
    float* b1 = S1 + kcur * D_DIM + col0;
    atomicAdd(b1 + 0, a1.x); atomicAdd(b1 + 1, a1.y);
    atomicAdd(b1 + 2, a1.z); atomicAdd(b1 + 3, a1.w);
#pragma unroll
    for (int o = 32; o > 0; o >>= 1) s2c += __shfl_down(s2c, o, 64);
    if (lane == 0) wred[wid] = s2c;
    __syncthreads();
    if (tid == 0)
        atomicAdd(&s2sum[kcur], wred[0] + wred[1] + wred[2] + wred[3]);
}

// Kernel C: 60 blocks (class k x column-slice g). Per cell add
// -S1^2/(cnt^2*D*K); one thread also adds S2sum_k/(cnt*D*K).
__global__ __launch_bounds__(256) void wcss_finish(const float* __restrict__ S1,
                                                   const float* __restrict__ s2sum,
                                                   const int* __restrict__ counts,
                                                   float* __restrict__ out) {
    __shared__ float sbuf[256];
    const int tid = threadIdx.x;
    const int k = blockIdx.x / NGROUPS;
    const int g = blockIdx.x % NGROUPS;
    const float cnt = (float)counts[k];
    const float inv = 1.0f / (cnt * cnt * (float)D_DIM * (float)K_CLS);

    const float4 v = *(const float4*)(S1 + k * D_DIM + g * COLS_PER_BLOCK + tid * 4);
    float t = -(v.x * v.x + v.y * v.y + v.z * v.z + v.w * v.w) * inv;
    if (g == 0 && tid == 0)
        t += s2sum[k] / (cnt * (float)D_DIM * (float)K_CLS);

    sbuf[tid] = t;
    __syncthreads();
    for (int off = 128; off > 0; off >>= 1) {
        if (tid < off) sbuf[tid] += sbuf[tid + off];
        __syncthreads();
    }
    if (tid == 0) atomicAdd(out, sbuf[0]);
}

extern "C" void kernel_launch(void* const* d_in, const int* in_sizes, int n_in,
                              void* d_out, int out_size, void* d_ws, size_t ws_size,
                              hipStream_t stream) {
    const float* X = (const float*)d_in[0];
    const int* y = (const int*)d_in[1];

    float* S1 = (float*)d_ws;                       // K*D floats
    float* s2sum = S1 + K_CLS * D_DIM;              // K floats
    int* counts = (int*)(s2sum + K_CLS);            // K ints
    int* sorted = counts + K_CLS;                   // N ints
    float* out = (float*)d_out;

    hipMemsetAsync(S1, 0, (K_CLS * D_DIM + K_CLS) * sizeof(float), stream);
    hipMemsetAsync(out, 0, sizeof(float), stream);

    build_sort<<<dim3(1), dim3(1024), 0, stream>>>(y, counts, sorted);
    wcss_accum<<<dim3(NGROUPS, NWIN), dim3(256), 0, stream>>>(X, sorted, S1, s2sum);
    wcss_finish<<<dim3(K_CLS * NGROUPS), dim3(256), 0, stream>>>(S1, s2sum,
                                                                 counts, out);
}